// Round 5
// baseline (1155.331 us; speedup 1.0000x reference)
//
#include <hip/hip_runtime.h>
#include <math.h>

#define KNB 20
constexpr float BN_INV = 0.9999950000374997f;  // 1/sqrt(1+1e-5)
constexpr float SLOPE = 0.2f;

__device__ __forceinline__ float lrelu(float v){ return v >= 0.f ? v : SLOPE*v; }

// ---------------- transpose x (B,3,N) -> pts (B,N,3) ----------------
__global__ void transpose_x_kernel(const float* __restrict__ x, float* __restrict__ pts, int N){
  int i = blockIdx.x*blockDim.x + threadIdx.x;
  if (i >= 16*N) return;
  int b = i / N, n = i % N;
  const float* xb = x + (size_t)b*3*N;
  float* p = pts + (size_t)i*3;
  p[0]=xb[n]; p[1]=xb[N+n]; p[2]=xb[2*N+n];
}

// ---------------- kNN: one wave per query row, register top-k extraction ----------------
template<int N>
__global__ __launch_bounds__(256) void knn_kernel(const float* __restrict__ pts, int* __restrict__ idx){
#pragma clang fp contract(off)
  constexpr int E = N/64;
  __shared__ float4 sp[N];
  int b = blockIdx.y;
  int t = threadIdx.x;
  const float* pb = pts + (size_t)b*N*3;
  for (int e = t; e < N; e += 256){
    float x0=pb[e*3], x1=pb[e*3+1], x2=pb[e*3+2];
    sp[e] = make_float4(x0, x1, x2, (x0*x0 + x1*x1) + x2*x2);
  }
  __syncthreads();
  int wave = t >> 6, lane = t & 63;
  int row = blockIdx.x*4 + wave;
  float4 P = sp[row];
  float nd[E];
  #pragma unroll
  for (int i=0;i<E;++i){
    float4 Q = sp[lane + i*64];
    float inner = (P.x*Q.x + P.y*Q.y) + P.z*Q.z;
    nd[i] = (2.0f*inner - P.w) - Q.w;
  }
  int myout = 0;
  for (int j=0;j<KNB;++j){
    float bv = nd[0]; int bi = lane;
    #pragma unroll
    for (int i=1;i<E;++i){
      if (nd[i] > bv){ bv = nd[i]; bi = lane + i*64; }
    }
    #pragma unroll
    for (int off=1; off<64; off<<=1){
      float ov = __shfl_xor(bv, off);
      int oi = __shfl_xor(bi, off);
      if (ov > bv || (ov == bv && oi < bi)){ bv = ov; bi = oi; }
    }
    if (lane == j) myout = bi;
    if (lane == (bi & 63)){
      int slot = bi >> 6;
      #pragma unroll
      for (int i=0;i<E;++i) if (i == slot) nd[i] = -INFINITY;
    }
  }
  if (lane < KNB) idx[((size_t)b*N + row)*KNB + lane] = myout;
}

// ---------------- covariance of kNN diffs + analytic 3x3 symmetric eigenvalues ----------------
template<int N>
__global__ void cov_eig_kernel(const float* __restrict__ pts, const int* __restrict__ idx,
                               float* __restrict__ eigval){
  int i = blockIdx.x*blockDim.x + threadIdx.x;
  if (i >= 16*N) return;
  int b = i / N, n = i % N;
  const float* pb = pts + (size_t)b*N*3;
  const int* ix = idx + (size_t)i*KNB;
  float cx = pb[n*3], cy = pb[n*3+1], cz = pb[n*3+2];
  float c00=0,c01=0,c02=0,c11=0,c12=0,c22=0;
  for (int k=0;k<KNB;++k){
    int m = ix[k];
    float dx = pb[m*3]-cx, dy = pb[m*3+1]-cy, dz = pb[m*3+2]-cz;
    c00 += dx*dx; c01 += dx*dy; c02 += dx*dz;
    c11 += dy*dy; c12 += dy*dz; c22 += dz*dz;
  }
  double a00=c00,a01=c01,a02=c02,a11=c11,a12=c12,a22=c22;
  double p1 = a01*a01 + a02*a02 + a12*a12;
  double q = (a00+a11+a22)/3.0;
  double b00=a00-q, b11=a11-q, b22=a22-q;
  double p2 = b00*b00+b11*b11+b22*b22 + 2.0*p1;
  double e0,e1,e2;
  if (p2 <= 0.0){
    e0=e1=e2=q;
  } else {
    double p = sqrt(p2/6.0);
    double det = b00*(b11*b22 - a12*a12) - a01*(a01*b22 - a12*a02) + a02*(a01*a12 - b11*a02);
    double r = det / (2.0*p*p*p);
    r = fmin(1.0, fmax(-1.0, r));
    double phi = acos(r)/3.0;
    double big = q + 2.0*p*cos(phi);
    double sml = q + 2.0*p*cos(phi + 2.0943951023931953);
    double mid = 3.0*q - big - sml;
    e0 = sml; e1 = mid; e2 = big;
  }
  float* ev = eigval + (size_t)i*3;
  ev[0]=(float)e0; ev[1]=(float)e1; ev[2]=(float)e2;
}

// ---------------- stage1: build 13-ch graph feature + conv1 + BN + lrelu + max_k ----------------
__global__ __launch_bounds__(64) void stage1_kernel(const float* __restrict__ pts, const float* __restrict__ eigval,
   const int* __restrict__ idx_eu, const int* __restrict__ idx_ei,
   const float* __restrict__ w, const float* __restrict__ g, const float* __restrict__ bb,
   float* __restrict__ x1, int N){
  __shared__ float feat[13][KNB];
  int i = blockIdx.x; int b = i / N, n = i % N;
  int t = threadIdx.x;
  const float* pb = pts + (size_t)b*N*3;
  const float* eb = eigval + (size_t)b*N*3;
  if (t < KNB){
    int ieu = idx_eu[(size_t)i*KNB + t];
    int iei = idx_ei[(size_t)i*KNB + t];
    float d2 = 0.f;
    #pragma unroll
    for (int f=0; f<3; ++f){
      float nx = pb[ieu*3+f], xx = pb[n*3+f];
      float dfv = nx - xx;
      feat[f][t] = dfv; feat[3+f][t] = nx;
      float ne = eb[iei*3+f], ee = eb[n*3+f];
      feat[6+f][t] = ne - ee; feat[9+f][t] = ne;
      d2 += dfv*dfv;
    }
    feat[12][t] = sqrtf(fmaxf(d2, 1e-12f));
  }
  __syncthreads();
  float wr[13];
  #pragma unroll
  for (int c=0;c<13;++c) wr[c] = w[t*13+c];
  float sg = BN_INV * g[t], sb = bb[t];
  float mx = -INFINITY;
  for (int k=0;k<KNB;++k){
    float s = 0.f;
    #pragma unroll
    for (int c=0;c<13;++c) s = fmaf(wr[c], feat[c][k], s);
    mx = fmaxf(mx, lrelu(fmaf(s, sg, sb)));
  }
  x1[(size_t)i*64 + t] = mx;
}

// ---------------- farthest point sampling: single wave, register dists, no spills ----------------
template<int N, int M>
__global__ __launch_bounds__(64, 1) void fps_kernel(const float* __restrict__ pts, int* __restrict__ idout){
#pragma clang fp contract(off)
  constexpr int E = N/64;
  __shared__ float4 sp[N];
  int b = blockIdx.x, lane = threadIdx.x;
  const float* pb = pts + (size_t)b*N*3;
  for (int e=lane; e<N; e+=64){
    sp[e] = make_float4(pb[e*3], pb[e*3+1], pb[e*3+2], 0.f);
  }
  __syncthreads();
  float px[E],py[E],pz[E],dist[E];
  #pragma unroll
  for (int i=0;i<E;++i){
    float4 q = sp[i*64 + lane];
    px[i]=q.x; py[i]=q.y; pz[i]=q.z;
    dist[i]=1e10f;
  }
  int last = 0;
  if (lane==0) idout[(size_t)b*M] = 0;
  for (int s=1; s<M; ++s){
    float4 L = sp[last];
    float bv=-INFINITY; int bi=0x7fffffff;
    #pragma unroll
    for (int i=0;i<E;++i){
      float dx=px[i]-L.x, dy=py[i]-L.y, dz=pz[i]-L.z;
      float d2 = (dx*dx + dy*dy) + dz*dz;
      float dd = fminf(dist[i], d2);
      dist[i]=dd;
      if (dd > bv){ bv=dd; bi=i*64+lane; }
    }
    #pragma unroll
    for (int off=1; off<64; off<<=1){
      float ov = __shfl_xor(bv, off);
      int oi = __shfl_xor(bi, off);
      if (ov > bv || (ov == bv && oi < bi)){ bv=ov; bi=oi; }
    }
    last = bi;
    if (lane==0) idout[(size_t)b*M + s] = last;
  }
}

// ---------------- gathers ----------------
__global__ void gather_pts_kernel(const float* __restrict__ pts, const int* __restrict__ id,
                                  float* __restrict__ outp, int N, int M){
  int i = blockIdx.x*blockDim.x + threadIdx.x;
  if (i >= 16*M) return;
  int b=i/M;
  int src = id[i];
  const float* p = pts + ((size_t)b*N + src)*3;
  float* o = outp + (size_t)i*3;
  o[0]=p[0]; o[1]=p[1]; o[2]=p[2];
}

__global__ void gather_feat_kernel(const float* __restrict__ xin, const int* __restrict__ id,
                                   float* __restrict__ outp, int N, int M, int C){
  int i = blockIdx.x*blockDim.x + threadIdx.x;
  if (i >= 16*M*C) return;
  int c = i % C; int rest = i / C; int b = rest / M, s = rest % M;
  int src = id[(size_t)b*M + s];
  outp[i] = xin[((size_t)b*N + src)*C + c];
}

// ---------------- combine conv weights: W1=wa+wb, W2=wc+wd, Wb=wa+wc, quad-packed [c/4][o][4] ----------------
template<int COUT>
__global__ void combine_w_kernel(const float* __restrict__ w,
                                 float* __restrict__ W1q, float* __restrict__ W2q, float* __restrict__ Wbq){
  int i = blockIdx.x*blockDim.x + threadIdx.x;
  if (i >= COUT*64) return;
  int o = i >> 6, c = i & 63;
  float wa = w[(size_t)o*256 + c], wb = w[(size_t)o*256 + 64 + c];
  float wc = w[(size_t)o*256 + 128 + c], wd = w[(size_t)o*256 + 192 + c];
  int q = (((c>>2)*COUT) + o)*4 + (c&3);
  W1q[q] = wa + wb;
  W2q[q] = wc + wd;
  Wbq[q] = wa + wc;
}

// ---------------- fused group_layer x2 + conv + BN + lrelu + max_k (stages 2,3) ----------------
// weights pre-combined & transposed (coalesced float4 loads per thread=output)
template<int COUT, int N>
__global__ __launch_bounds__(COUT) void groupconv_kernel(
    const float* __restrict__ xin,  // (B,N,64)
    const int* __restrict__ idx_eu, const int* __restrict__ idx_ei,
    const float* __restrict__ W1q, const float* __restrict__ W2q, const float* __restrict__ Wbq,
    const float* __restrict__ g, const float* __restrict__ bb,
    float* __restrict__ xout){      // (B,N,COUT)
  __shared__ float sEU[KNB][68], sEI[KNB][68], sC[64];
  __shared__ int sIdx[2*KNB];
  int i = blockIdx.x; int b = i / N, n = i % N;
  int t = threadIdx.x;
  if (t < KNB) sIdx[t] = idx_eu[(size_t)i*KNB + t];
  else if (t < 2*KNB) sIdx[t] = idx_ei[(size_t)i*KNB + (t-KNB)];
  if (t < 64) sC[t] = xin[((size_t)b*N + n)*64 + t];
  __syncthreads();
  const float* xb = xin + (size_t)b*N*64;
  for (int e = t; e < KNB*64; e += COUT){
    int k = e >> 6, c = e & 63;
    sEU[k][c] = xb[(size_t)sIdx[k]*64 + c];
    sEI[k][c] = xb[(size_t)sIdx[KNB+k]*64 + c];
  }
  __syncthreads();
  float acc[KNB];
  #pragma unroll
  for (int k=0;k<KNB;++k) acc[k]=0.f;
  float base = 0.f;
  #pragma unroll 4
  for (int c4=0; c4<16; ++c4){
    float4 w1 = *(const float4*)&W1q[((size_t)c4*COUT + t)*4];
    float4 w2 = *(const float4*)&W2q[((size_t)c4*COUT + t)*4];
    float4 wbv= *(const float4*)&Wbq[((size_t)c4*COUT + t)*4];
    float4 xc = *(const float4*)&sC[c4*4];
    base = fmaf(wbv.x, xc.x, base);
    base = fmaf(wbv.y, xc.y, base);
    base = fmaf(wbv.z, xc.z, base);
    base = fmaf(wbv.w, xc.w, base);
    #pragma unroll
    for (int k=0;k<KNB;++k){
      float4 eu = *(const float4*)&sEU[k][c4*4];
      float4 ei = *(const float4*)&sEI[k][c4*4];
      float s = acc[k];
      s = fmaf(w1.x, eu.x, s); s = fmaf(w2.x, ei.x, s);
      s = fmaf(w1.y, eu.y, s); s = fmaf(w2.y, ei.y, s);
      s = fmaf(w1.z, eu.z, s); s = fmaf(w2.z, ei.z, s);
      s = fmaf(w1.w, eu.w, s); s = fmaf(w2.w, ei.w, s);
      acc[k] = s;
    }
  }
  float sg = BN_INV * g[t], sb = bb[t];
  float mx = -INFINITY;
  #pragma unroll
  for (int k=0;k<KNB;++k){
    float v = fmaf(acc[k] - base, sg, sb);
    mx = fmaxf(mx, lrelu(v));
  }
  xout[(size_t)i*COUT + t] = mx;
}

// ---------------- conv5 as tiled GEMM: 64n x 64o tile, K=256 in 4 chunks ----------------
__global__ __launch_bounds__(256) void conv5_gemm_kernel(
    const float* __restrict__ x1dd, const float* __restrict__ x2d, const float* __restrict__ x3,
    const float* __restrict__ w, const float* __restrict__ g, const float* __restrict__ bb,
    float* __restrict__ pmax, float* __restrict__ psum){
  __shared__ float sA[64][68];   // n x k-chunk (pad 68: 16B-aligned rows)
  __shared__ float sB[64][68];   // o x k-chunk
  int otile = blockIdx.x, ntile = blockIdx.y, b = blockIdx.z;
  int t = threadIdx.x;
  int tx = t & 15, ty = t >> 4;
  float acc[4][4];
  #pragma unroll
  for (int i=0;i<4;++i)
    #pragma unroll
    for (int j=0;j<4;++j) acc[i][j] = 0.f;
  for (int kc=0; kc<4; ++kc){
    #pragma unroll 4
    for (int e = t; e < 4096; e += 256){
      int nl = e >> 6, kl = e & 63;
      int n = ntile*64 + nl;
      float v;
      if (kc == 0)      v = x1dd[((size_t)b*256 + n)*64 + kl];
      else if (kc == 1) v = x2d [((size_t)b*256 + n)*64 + kl];
      else              v = x3  [((size_t)b*256 + n)*128 + (kc-2)*64 + kl];
      sA[nl][kl] = v;
    }
    #pragma unroll 4
    for (int e = t; e < 4096; e += 256){
      int ol = e >> 6, kl = e & 63;
      sB[ol][kl] = w[((size_t)(otile*64 + ol))*256 + kc*64 + kl];
    }
    __syncthreads();
    #pragma unroll
    for (int k4=0; k4<16; ++k4){
      float4 a0 = *(const float4*)&sA[ty*4+0][k4*4];
      float4 a1 = *(const float4*)&sA[ty*4+1][k4*4];
      float4 a2 = *(const float4*)&sA[ty*4+2][k4*4];
      float4 a3 = *(const float4*)&sA[ty*4+3][k4*4];
      float4 b0 = *(const float4*)&sB[tx*4+0][k4*4];
      float4 b1 = *(const float4*)&sB[tx*4+1][k4*4];
      float4 b2 = *(const float4*)&sB[tx*4+2][k4*4];
      float4 b3 = *(const float4*)&sB[tx*4+3][k4*4];
      float4 A[4] = {a0,a1,a2,a3};
      float4 Bv[4] = {b0,b1,b2,b3};
      #pragma unroll
      for (int i=0;i<4;++i)
        #pragma unroll
        for (int j=0;j<4;++j){
          float s = acc[i][j];
          s = fmaf(A[i].x, Bv[j].x, s);
          s = fmaf(A[i].y, Bv[j].y, s);
          s = fmaf(A[i].z, Bv[j].z, s);
          s = fmaf(A[i].w, Bv[j].w, s);
          acc[i][j] = s;
        }
    }
    __syncthreads();
  }
  // epilogue: BN + lrelu, reduce max/sum over the 64 n-rows of this tile
  float sg[4], sbv[4];
  #pragma unroll
  for (int j=0;j<4;++j){
    int o = otile*64 + tx*4 + j;
    sg[j] = BN_INV*g[o]; sbv[j] = bb[o];
  }
  float mx[4], sm[4];
  #pragma unroll
  for (int j=0;j<4;++j){ mx[j]=-INFINITY; sm[j]=0.f; }
  #pragma unroll
  for (int i=0;i<4;++i)
    #pragma unroll
    for (int j=0;j<4;++j){
      float vv = lrelu(fmaf(acc[i][j], sg[j], sbv[j]));
      mx[j] = fmaxf(mx[j], vv);
      sm[j] += vv;
    }
  float* redM = &sA[0][0];        // 16 x 64
  float* redS = redM + 16*64;     // 16 x 64 (fits in sA: 64*68 floats)
  #pragma unroll
  for (int j=0;j<4;++j){
    redM[ty*64 + tx*4 + j] = mx[j];
    redS[ty*64 + tx*4 + j] = sm[j];
  }
  __syncthreads();
  if (t < 64){
    float m = -INFINITY, s = 0.f;
    #pragma unroll
    for (int r=0;r<16;++r){
      m = fmaxf(m, redM[r*64 + t]);
      s += redS[r*64 + t];
    }
    int o = otile*64 + t;
    pmax[((size_t)b*1024 + o)*4 + ntile] = m;
    psum[((size_t)b*1024 + o)*4 + ntile] = s;
  }
}

__global__ void head_reduce_kernel(const float* __restrict__ pmax, const float* __restrict__ psum,
                                   float* __restrict__ h2){
  int i = blockIdx.x*blockDim.x + threadIdx.x;
  if (i >= 16*1024) return;
  int b = i >> 10, o = i & 1023;
  const float* pm = pmax + (size_t)i*4;
  const float* ps = psum + (size_t)i*4;
  float mx = fmaxf(fmaxf(pm[0],pm[1]), fmaxf(pm[2],pm[3]));
  float sm = (ps[0]+ps[1])+(ps[2]+ps[3]);
  h2[(size_t)b*2048 + o] = mx;
  h2[(size_t)b*2048 + 1024 + o] = sm * (1.0f/256.0f);
}

// ---------------- head linears ----------------
__global__ __launch_bounds__(256) void lin1_kernel(const float* __restrict__ h2, const float* __restrict__ w,
    const float* __restrict__ g, const float* __restrict__ bb, float* __restrict__ y1){
  __shared__ float sh[2048];
  int b = blockIdx.y; int o = blockIdx.x*256 + threadIdx.x;
  for (int e=threadIdx.x; e<2048; e+=256) sh[e] = h2[(size_t)b*2048+e];
  __syncthreads();
  const float* wr = w + (size_t)o*2048;
  float acc=0.f;
  for (int c=0;c<2048;++c) acc = fmaf(wr[c], sh[c], acc);
  y1[(size_t)b*512+o] = lrelu(fmaf(acc, BN_INV*g[o], bb[o]));
}

__global__ __launch_bounds__(256) void lin2_kernel(const float* __restrict__ y1, const float* __restrict__ w,
    const float* __restrict__ lb, const float* __restrict__ g, const float* __restrict__ bb,
    float* __restrict__ y2){
  __shared__ float sh[512];
  int b = blockIdx.x; int o = threadIdx.x;
  for (int e=o; e<512; e+=256) sh[e]=y1[(size_t)b*512+e];
  __syncthreads();
  const float* wr = w + (size_t)o*512;
  float acc=0.f;
  for (int c=0;c<512;++c) acc = fmaf(wr[c], sh[c], acc);
  acc += lb[o];
  y2[(size_t)b*256+o] = lrelu(fmaf(acc, BN_INV*g[o], bb[o]));
}

__global__ __launch_bounds__(64) void lin3_kernel(const float* __restrict__ y2, const float* __restrict__ w,
    const float* __restrict__ lb, float* __restrict__ outp){
  __shared__ float sh[256];
  int b = blockIdx.x; int t = threadIdx.x;
  for (int e=t; e<256; e+=64) sh[e]=y2[(size_t)b*256+e];
  __syncthreads();
  if (t < 40){
    const float* wr = w + (size_t)t*256;
    float acc=0.f;
    for (int c=0;c<256;++c) acc = fmaf(wr[c], sh[c], acc);
    outp[(size_t)b*40+t] = acc + lb[t];
  }
}

extern "C" void kernel_launch(void* const* d_in, const int* in_sizes, int n_in,
                              void* d_out, int out_size, void* d_ws, size_t ws_size,
                              hipStream_t stream) {
  const float* x      = (const float*)d_in[0];
  const float* conv1w = (const float*)d_in[1];
  const float* bn1g   = (const float*)d_in[2];
  const float* bn1b   = (const float*)d_in[3];
  const float* conv2w = (const float*)d_in[4];
  const float* bn2g   = (const float*)d_in[5];
  const float* bn2b   = (const float*)d_in[6];
  const float* conv3w = (const float*)d_in[7];
  const float* bn3g   = (const float*)d_in[8];
  const float* bn3b   = (const float*)d_in[9];
  const float* conv5w = (const float*)d_in[10];
  const float* bn5g   = (const float*)d_in[11];
  const float* bn5b   = (const float*)d_in[12];
  const float* lin1w  = (const float*)d_in[13];
  const float* bn6g   = (const float*)d_in[14];
  const float* bn6b   = (const float*)d_in[15];
  const float* lin2w  = (const float*)d_in[16];
  const float* lin2b  = (const float*)d_in[17];
  const float* bn7g   = (const float*)d_in[18];
  const float* bn7b   = (const float*)d_in[19];
  const float* lin3w  = (const float*)d_in[20];
  const float* lin3b  = (const float*)d_in[21];
  float* outp = (float*)d_out;

  char* ws = (char*)d_ws;
  size_t off = 0;
  auto alloc = [&](size_t bytes)->char*{
    off = (off + 255) & ~(size_t)255;
    char* p = ws + off; off += bytes; return p;
  };
  const int B=16, N1=1024, N2=512, N3=256;
  float* pts1 = (float*)alloc((size_t)B*N1*3*4);
  int*   ieu1 = (int*)alloc((size_t)B*N1*KNB*4);
  float* eig1 = (float*)alloc((size_t)B*N1*3*4);
  int*   iei1 = (int*)alloc((size_t)B*N1*KNB*4);
  float* x1   = (float*)alloc((size_t)B*N1*64*4);
  int*   id2  = (int*)alloc((size_t)B*N2*4);
  float* pts2 = (float*)alloc((size_t)B*N2*3*4);
  float* x1d  = (float*)alloc((size_t)B*N2*64*4);
  int*   ieu2 = (int*)alloc((size_t)B*N2*KNB*4);
  float* eig2 = (float*)alloc((size_t)B*N2*3*4);
  int*   iei2 = (int*)alloc((size_t)B*N2*KNB*4);
  float* x2   = (float*)alloc((size_t)B*N2*64*4);
  int*   id3  = (int*)alloc((size_t)B*N3*4);
  float* pts3 = (float*)alloc((size_t)B*N3*3*4);
  float* x2d  = (float*)alloc((size_t)B*N3*64*4);
  float* x1dd = (float*)alloc((size_t)B*N3*64*4);
  int*   ieu3 = (int*)alloc((size_t)B*N3*KNB*4);
  float* eig3 = (float*)alloc((size_t)B*N3*3*4);
  int*   iei3 = (int*)alloc((size_t)B*N3*KNB*4);
  float* x3   = (float*)alloc((size_t)B*N3*128*4);
  float* pmax = (float*)alloc((size_t)B*1024*4*4);
  float* psum = (float*)alloc((size_t)B*1024*4*4);
  float* h2   = (float*)alloc((size_t)B*2048*4);
  float* y1   = (float*)alloc((size_t)B*512*4);
  float* y2   = (float*)alloc((size_t)B*256*4);
  float* W1q2 = (float*)alloc((size_t)64*64*4);
  float* W2q2 = (float*)alloc((size_t)64*64*4);
  float* Wbq2 = (float*)alloc((size_t)64*64*4);
  float* W1q3 = (float*)alloc((size_t)128*64*4);
  float* W2q3 = (float*)alloc((size_t)128*64*4);
  float* Wbq3 = (float*)alloc((size_t)128*64*4);

  combine_w_kernel<64><<<(64*64+255)/256, 256, 0, stream>>>(conv2w, W1q2, W2q2, Wbq2);
  combine_w_kernel<128><<<(128*64+255)/256, 256, 0, stream>>>(conv3w, W1q3, W2q3, Wbq3);
  transpose_x_kernel<<<(B*N1+255)/256, 256, 0, stream>>>(x, pts1, N1);
  knn_kernel<1024><<<dim3(256,16), 256, 0, stream>>>(pts1, ieu1);
  cov_eig_kernel<1024><<<(B*N1+255)/256, 256, 0, stream>>>(pts1, ieu1, eig1);
  knn_kernel<1024><<<dim3(256,16), 256, 0, stream>>>(eig1, iei1);
  stage1_kernel<<<B*N1, 64, 0, stream>>>(pts1, eig1, ieu1, iei1, conv1w, bn1g, bn1b, x1, N1);
  fps_kernel<1024,512><<<16, 64, 0, stream>>>(pts1, id2);
  gather_pts_kernel<<<(B*N2+255)/256, 256, 0, stream>>>(pts1, id2, pts2, N1, N2);
  gather_feat_kernel<<<(B*N2*64+255)/256, 256, 0, stream>>>(x1, id2, x1d, N1, N2, 64);
  knn_kernel<512><<<dim3(128,16), 256, 0, stream>>>(pts2, ieu2);
  cov_eig_kernel<512><<<(B*N2+255)/256, 256, 0, stream>>>(pts2, ieu2, eig2);
  knn_kernel<512><<<dim3(128,16), 256, 0, stream>>>(eig2, iei2);
  groupconv_kernel<64,512><<<B*N2, 64, 0, stream>>>(x1d, ieu2, iei2, W1q2, W2q2, Wbq2, bn2g, bn2b, x2);
  fps_kernel<512,256><<<16, 64, 0, stream>>>(pts2, id3);
  gather_pts_kernel<<<(B*N3+255)/256, 256, 0, stream>>>(pts2, id3, pts3, N2, N3);
  gather_feat_kernel<<<(B*N3*64+255)/256, 256, 0, stream>>>(x2, id3, x2d, N2, N3, 64);
  gather_feat_kernel<<<(B*N3*64+255)/256, 256, 0, stream>>>(x1d, id3, x1dd, N2, N3, 64);
  knn_kernel<256><<<dim3(64,16), 256, 0, stream>>>(pts3, ieu3);
  cov_eig_kernel<256><<<(B*N3+255)/256, 256, 0, stream>>>(pts3, ieu3, eig3);
  knn_kernel<256><<<dim3(64,16), 256, 0, stream>>>(eig3, iei3);
  groupconv_kernel<128,256><<<B*N3, 128, 0, stream>>>(x2d, ieu3, iei3, W1q3, W2q3, Wbq3, bn3g, bn3b, x3);
  conv5_gemm_kernel<<<dim3(16,4,16), 256, 0, stream>>>(x1dd, x2d, x3, conv5w, bn5g, bn5b, pmax, psum);
  head_reduce_kernel<<<(B*1024+255)/256, 256, 0, stream>>>(pmax, psum, h2);
  lin1_kernel<<<dim3(2,16), 256, 0, stream>>>(h2, lin1w, bn6g, bn6b, y1);
  lin2_kernel<<<16, 256, 0, stream>>>(y1, lin2w, lin2b, bn7g, bn7b, y2);
  lin3_kernel<<<16, 64, 0, stream>>>(y2, lin3w, lin3b, outp);
}

// Round 6
// 970.081 us; speedup vs baseline: 1.1910x; 1.1910x over previous
//
#include <hip/hip_runtime.h>
#include <math.h>

#define KNB 20
constexpr float BN_INV = 0.9999950000374997f;  // 1/sqrt(1+1e-5)
constexpr float SLOPE = 0.2f;

__device__ __forceinline__ float lrelu(float v){ return v >= 0.f ? v : SLOPE*v; }

// ---------------- transpose x (B,3,N) -> pts (B,N,3) ----------------
__global__ void transpose_x_kernel(const float* __restrict__ x, float* __restrict__ pts, int N){
  int i = blockIdx.x*blockDim.x + threadIdx.x;
  if (i >= 16*N) return;
  int b = i / N, n = i % N;
  const float* xb = x + (size_t)b*3*N;
  float* p = pts + (size_t)i*3;
  p[0]=xb[n]; p[1]=xb[N+n]; p[2]=xb[2*N+n];
}

// ---------------- kNN: one wave per query row, register top-k extraction ----------------
template<int N>
__global__ __launch_bounds__(256) void knn_kernel(const float* __restrict__ pts, int* __restrict__ idx){
#pragma clang fp contract(off)
  constexpr int E = N/64;
  __shared__ float4 sp[N];
  int b = blockIdx.y;
  int t = threadIdx.x;
  const float* pb = pts + (size_t)b*N*3;
  for (int e = t; e < N; e += 256){
    float x0=pb[e*3], x1=pb[e*3+1], x2=pb[e*3+2];
    sp[e] = make_float4(x0, x1, x2, (x0*x0 + x1*x1) + x2*x2);
  }
  __syncthreads();
  int wave = t >> 6, lane = t & 63;
  int row = blockIdx.x*4 + wave;
  float4 P = sp[row];
  float nd[E];
  #pragma unroll
  for (int i=0;i<E;++i){
    float4 Q = sp[lane + i*64];
    float inner = (P.x*Q.x + P.y*Q.y) + P.z*Q.z;
    nd[i] = (2.0f*inner - P.w) - Q.w;
  }
  int myout = 0;
  for (int j=0;j<KNB;++j){
    float bv = nd[0]; int bi = lane;
    #pragma unroll
    for (int i=1;i<E;++i){
      if (nd[i] > bv){ bv = nd[i]; bi = lane + i*64; }
    }
    #pragma unroll
    for (int off=1; off<64; off<<=1){
      float ov = __shfl_xor(bv, off);
      int oi = __shfl_xor(bi, off);
      if (ov > bv || (ov == bv && oi < bi)){ bv = ov; bi = oi; }
    }
    if (lane == j) myout = bi;
    if (lane == (bi & 63)){
      int slot = bi >> 6;
      #pragma unroll
      for (int i=0;i<E;++i) if (i == slot) nd[i] = -INFINITY;
    }
  }
  if (lane < KNB) idx[((size_t)b*N + row)*KNB + lane] = myout;
}

// ---------------- covariance of kNN diffs + analytic 3x3 symmetric eigenvalues ----------------
template<int N>
__global__ void cov_eig_kernel(const float* __restrict__ pts, const int* __restrict__ idx,
                               float* __restrict__ eigval){
  int i = blockIdx.x*blockDim.x + threadIdx.x;
  if (i >= 16*N) return;
  int b = i / N, n = i % N;
  const float* pb = pts + (size_t)b*N*3;
  const int* ix = idx + (size_t)i*KNB;
  float cx = pb[n*3], cy = pb[n*3+1], cz = pb[n*3+2];
  float c00=0,c01=0,c02=0,c11=0,c12=0,c22=0;
  for (int k=0;k<KNB;++k){
    int m = ix[k];
    float dx = pb[m*3]-cx, dy = pb[m*3+1]-cy, dz = pb[m*3+2]-cz;
    c00 += dx*dx; c01 += dx*dy; c02 += dx*dz;
    c11 += dy*dy; c12 += dy*dz; c22 += dz*dz;
  }
  double a00=c00,a01=c01,a02=c02,a11=c11,a12=c12,a22=c22;
  double p1 = a01*a01 + a02*a02 + a12*a12;
  double q = (a00+a11+a22)/3.0;
  double b00=a00-q, b11=a11-q, b22=a22-q;
  double p2 = b00*b00+b11*b11+b22*b22 + 2.0*p1;
  double e0,e1,e2;
  if (p2 <= 0.0){
    e0=e1=e2=q;
  } else {
    double p = sqrt(p2/6.0);
    double det = b00*(b11*b22 - a12*a12) - a01*(a01*b22 - a12*a02) + a02*(a01*a12 - b11*a02);
    double r = det / (2.0*p*p*p);
    r = fmin(1.0, fmax(-1.0, r));
    double phi = acos(r)/3.0;
    double big = q + 2.0*p*cos(phi);
    double sml = q + 2.0*p*cos(phi + 2.0943951023931953);
    double mid = 3.0*q - big - sml;
    e0 = sml; e1 = mid; e2 = big;
  }
  float* ev = eigval + (size_t)i*3;
  ev[0]=(float)e0; ev[1]=(float)e1; ev[2]=(float)e2;
}

// ---------------- stage1: build 13-ch graph feature + conv1 + BN + lrelu + max_k ----------------
__global__ __launch_bounds__(64) void stage1_kernel(const float* __restrict__ pts, const float* __restrict__ eigval,
   const int* __restrict__ idx_eu, const int* __restrict__ idx_ei,
   const float* __restrict__ w, const float* __restrict__ g, const float* __restrict__ bb,
   float* __restrict__ x1, int N){
  __shared__ float feat[13][KNB];
  int i = blockIdx.x; int b = i / N, n = i % N;
  int t = threadIdx.x;
  const float* pb = pts + (size_t)b*N*3;
  const float* eb = eigval + (size_t)b*N*3;
  if (t < KNB){
    int ieu = idx_eu[(size_t)i*KNB + t];
    int iei = idx_ei[(size_t)i*KNB + t];
    float d2 = 0.f;
    #pragma unroll
    for (int f=0; f<3; ++f){
      float nx = pb[ieu*3+f], xx = pb[n*3+f];
      float dfv = nx - xx;
      feat[f][t] = dfv; feat[3+f][t] = nx;
      float ne = eb[iei*3+f], ee = eb[n*3+f];
      feat[6+f][t] = ne - ee; feat[9+f][t] = ne;
      d2 += dfv*dfv;
    }
    feat[12][t] = sqrtf(fmaxf(d2, 1e-12f));
  }
  __syncthreads();
  float wr[13];
  #pragma unroll
  for (int c=0;c<13;++c) wr[c] = w[t*13+c];
  float sg = BN_INV * g[t], sb = bb[t];
  float mx = -INFINITY;
  for (int k=0;k<KNB;++k){
    float s = 0.f;
    #pragma unroll
    for (int c=0;c<13;++c) s = fmaf(wr[c], feat[c][k], s);
    mx = fmaxf(mx, lrelu(fmaf(s, sg, sb)));
  }
  x1[(size_t)i*64 + t] = mx;
}

// ---------------- farthest point sampling: single wave, forced-register dists, u64 argmax keys ----------------
template<int N, int M>
__global__ __launch_bounds__(64, 1) void fps_kernel(const float* __restrict__ pts, int* __restrict__ idout){
#pragma clang fp contract(off)
  constexpr int E = N/64;
  __shared__ float4 sp[N];
  int b = blockIdx.x, lane = threadIdx.x;
  const float* pb = pts + (size_t)b*N*3;
  for (int e=lane; e<N; e+=64){
    sp[e] = make_float4(pb[e*3], pb[e*3+1], pb[e*3+2], 0.f);
  }
  __syncthreads();
  float px[E],py[E],pz[E],dist[E];
  #pragma unroll
  for (int i=0;i<E;++i){
    float4 q = sp[i*64 + lane];
    px[i]=q.x; py[i]=q.y; pz[i]=q.z;
    dist[i]=1e10f;
    // make values opaque so the allocator cannot rematerialize from LDS each step
    asm volatile("" : "+v"(px[i]), "+v"(py[i]), "+v"(pz[i]));
  }
  unsigned int nl = ~(unsigned int)lane;   // ~(i*64+lane) == nl - i*64
  int last = 0;
  if (lane==0) idout[(size_t)b*M] = 0;
  for (int s=1; s<M; ++s){
    float4 L = sp[last];
    unsigned long long bk = 0ULL;
    #pragma unroll
    for (int i=0;i<E;++i){
      float dx=px[i]-L.x, dy=py[i]-L.y, dz=pz[i]-L.z;
      float d2 = (dx*dx + dy*dy) + dz*dz;
      float dd = fminf(dist[i], d2);
      dist[i]=dd;
      // key: high=float bits (monotone for dd>=0), low=~idx (min-index tie-break)
      unsigned long long k = ((unsigned long long)__float_as_uint(dd) << 32) | (unsigned int)(nl - i*64);
      if (k > bk) bk = k;
    }
    #pragma unroll
    for (int off=1; off<64; off<<=1){
      unsigned long long ok = __shfl_xor(bk, off);
      if (ok > bk) bk = ok;
    }
    last = (int)(~(unsigned int)bk);
    if (lane==0) idout[(size_t)b*M + s] = last;
  }
}

// ---------------- gathers ----------------
__global__ void gather_pts_kernel(const float* __restrict__ pts, const int* __restrict__ id,
                                  float* __restrict__ outp, int N, int M){
  int i = blockIdx.x*blockDim.x + threadIdx.x;
  if (i >= 16*M) return;
  int b=i/M;
  int src = id[i];
  const float* p = pts + ((size_t)b*N + src)*3;
  float* o = outp + (size_t)i*3;
  o[0]=p[0]; o[1]=p[1]; o[2]=p[2];
}

__global__ void gather_feat_kernel(const float* __restrict__ xin, const int* __restrict__ id,
                                   float* __restrict__ outp, int N, int M, int C){
  int i = blockIdx.x*blockDim.x + threadIdx.x;
  if (i >= 16*M*C) return;
  int c = i % C; int rest = i / C; int b = rest / M, s = rest % M;
  int src = id[(size_t)b*M + s];
  outp[i] = xin[((size_t)b*N + src)*C + c];
}

// ---------------- combine conv weights: W1=wa+wb, W2=wc+wd, Wb=wa+wc, quad-packed [c/4][o][4] ----------------
template<int COUT>
__global__ void combine_w_kernel(const float* __restrict__ w,
                                 float* __restrict__ W1q, float* __restrict__ W2q, float* __restrict__ Wbq){
  int i = blockIdx.x*blockDim.x + threadIdx.x;
  if (i >= COUT*64) return;
  int o = i >> 6, c = i & 63;
  float wa = w[(size_t)o*256 + c], wb = w[(size_t)o*256 + 64 + c];
  float wc = w[(size_t)o*256 + 128 + c], wd = w[(size_t)o*256 + 192 + c];
  int q = (((c>>2)*COUT) + o)*4 + (c&3);
  W1q[q] = wa + wb;
  W2q[q] = wc + wd;
  Wbq[q] = wa + wc;
}

// ---------------- fused group_layer x2 + conv + BN + lrelu + max_k (stages 2,3) ----------------
template<int COUT, int N>
__global__ __launch_bounds__(COUT) void groupconv_kernel(
    const float* __restrict__ xin,  // (B,N,64)
    const int* __restrict__ idx_eu, const int* __restrict__ idx_ei,
    const float* __restrict__ W1q, const float* __restrict__ W2q, const float* __restrict__ Wbq,
    const float* __restrict__ g, const float* __restrict__ bb,
    float* __restrict__ xout){      // (B,N,COUT)
  __shared__ float sEU[KNB][68], sEI[KNB][68], sC[64];
  __shared__ int sIdx[2*KNB];
  int i = blockIdx.x; int b = i / N, n = i % N;
  int t = threadIdx.x;
  if (t < KNB) sIdx[t] = idx_eu[(size_t)i*KNB + t];
  else if (t < 2*KNB) sIdx[t] = idx_ei[(size_t)i*KNB + (t-KNB)];
  if (t < 64) sC[t] = xin[((size_t)b*N + n)*64 + t];
  __syncthreads();
  const float* xb = xin + (size_t)b*N*64;
  for (int e = t; e < KNB*64; e += COUT){
    int k = e >> 6, c = e & 63;
    sEU[k][c] = xb[(size_t)sIdx[k]*64 + c];
    sEI[k][c] = xb[(size_t)sIdx[KNB+k]*64 + c];
  }
  __syncthreads();
  float acc[KNB];
  #pragma unroll
  for (int k=0;k<KNB;++k) acc[k]=0.f;
  float base = 0.f;
  #pragma unroll 4
  for (int c4=0; c4<16; ++c4){
    float4 w1 = *(const float4*)&W1q[((size_t)c4*COUT + t)*4];
    float4 w2 = *(const float4*)&W2q[((size_t)c4*COUT + t)*4];
    float4 wbv= *(const float4*)&Wbq[((size_t)c4*COUT + t)*4];
    float4 xc = *(const float4*)&sC[c4*4];
    base = fmaf(wbv.x, xc.x, base);
    base = fmaf(wbv.y, xc.y, base);
    base = fmaf(wbv.z, xc.z, base);
    base = fmaf(wbv.w, xc.w, base);
    #pragma unroll
    for (int k=0;k<KNB;++k){
      float4 eu = *(const float4*)&sEU[k][c4*4];
      float4 ei = *(const float4*)&sEI[k][c4*4];
      float s = acc[k];
      s = fmaf(w1.x, eu.x, s); s = fmaf(w2.x, ei.x, s);
      s = fmaf(w1.y, eu.y, s); s = fmaf(w2.y, ei.y, s);
      s = fmaf(w1.z, eu.z, s); s = fmaf(w2.z, ei.z, s);
      s = fmaf(w1.w, eu.w, s); s = fmaf(w2.w, ei.w, s);
      acc[k] = s;
    }
  }
  float sg = BN_INV * g[t], sb = bb[t];
  float mx = -INFINITY;
  #pragma unroll
  for (int k=0;k<KNB;++k){
    float v = fmaf(acc[k] - base, sg, sb);
    mx = fmaxf(mx, lrelu(v));
  }
  xout[(size_t)i*COUT + t] = mx;
}

// ---------------- conv5 as tiled GEMM: 64n x 64o tile, K=256 in 4 chunks ----------------
__global__ __launch_bounds__(256) void conv5_gemm_kernel(
    const float* __restrict__ x1dd, const float* __restrict__ x2d, const float* __restrict__ x3,
    const float* __restrict__ w, const float* __restrict__ g, const float* __restrict__ bb,
    float* __restrict__ pmax, float* __restrict__ psum){
  __shared__ float sA[64][68];   // n x k-chunk (pad 68: 16B-aligned rows)
  __shared__ float sB[64][68];   // o x k-chunk
  int otile = blockIdx.x, ntile = blockIdx.y, b = blockIdx.z;
  int t = threadIdx.x;
  int tx = t & 15, ty = t >> 4;
  float acc[4][4];
  #pragma unroll
  for (int i=0;i<4;++i)
    #pragma unroll
    for (int j=0;j<4;++j) acc[i][j] = 0.f;
  for (int kc=0; kc<4; ++kc){
    #pragma unroll 4
    for (int e = t; e < 4096; e += 256){
      int nl = e >> 6, kl = e & 63;
      int n = ntile*64 + nl;
      float v;
      if (kc == 0)      v = x1dd[((size_t)b*256 + n)*64 + kl];
      else if (kc == 1) v = x2d [((size_t)b*256 + n)*64 + kl];
      else              v = x3  [((size_t)b*256 + n)*128 + (kc-2)*64 + kl];
      sA[nl][kl] = v;
    }
    #pragma unroll 4
    for (int e = t; e < 4096; e += 256){
      int ol = e >> 6, kl = e & 63;
      sB[ol][kl] = w[((size_t)(otile*64 + ol))*256 + kc*64 + kl];
    }
    __syncthreads();
    #pragma unroll
    for (int k4=0; k4<16; ++k4){
      float4 a0 = *(const float4*)&sA[ty*4+0][k4*4];
      float4 a1 = *(const float4*)&sA[ty*4+1][k4*4];
      float4 a2 = *(const float4*)&sA[ty*4+2][k4*4];
      float4 a3 = *(const float4*)&sA[ty*4+3][k4*4];
      float4 b0 = *(const float4*)&sB[tx*4+0][k4*4];
      float4 b1 = *(const float4*)&sB[tx*4+1][k4*4];
      float4 b2 = *(const float4*)&sB[tx*4+2][k4*4];
      float4 b3 = *(const float4*)&sB[tx*4+3][k4*4];
      float4 A[4] = {a0,a1,a2,a3};
      float4 Bv[4] = {b0,b1,b2,b3};
      #pragma unroll
      for (int i=0;i<4;++i)
        #pragma unroll
        for (int j=0;j<4;++j){
          float s = acc[i][j];
          s = fmaf(A[i].x, Bv[j].x, s);
          s = fmaf(A[i].y, Bv[j].y, s);
          s = fmaf(A[i].z, Bv[j].z, s);
          s = fmaf(A[i].w, Bv[j].w, s);
          acc[i][j] = s;
        }
    }
    __syncthreads();
  }
  // epilogue: BN + lrelu, reduce max/sum over the 64 n-rows of this tile
  float sg[4], sbv[4];
  #pragma unroll
  for (int j=0;j<4;++j){
    int o = otile*64 + tx*4 + j;
    sg[j] = BN_INV*g[o]; sbv[j] = bb[o];
  }
  float mx[4], sm[4];
  #pragma unroll
  for (int j=0;j<4;++j){ mx[j]=-INFINITY; sm[j]=0.f; }
  #pragma unroll
  for (int i=0;i<4;++i)
    #pragma unroll
    for (int j=0;j<4;++j){
      float vv = lrelu(fmaf(acc[i][j], sg[j], sbv[j]));
      mx[j] = fmaxf(mx[j], vv);
      sm[j] += vv;
    }
  float* redM = &sA[0][0];        // 16 x 64
  float* redS = redM + 16*64;     // 16 x 64 (fits in sA: 64*68 floats)
  #pragma unroll
  for (int j=0;j<4;++j){
    redM[ty*64 + tx*4 + j] = mx[j];
    redS[ty*64 + tx*4 + j] = sm[j];
  }
  __syncthreads();
  if (t < 64){
    float m = -INFINITY, s = 0.f;
    #pragma unroll
    for (int r=0;r<16;++r){
      m = fmaxf(m, redM[r*64 + t]);
      s += redS[r*64 + t];
    }
    int o = otile*64 + t;
    pmax[((size_t)b*1024 + o)*4 + ntile] = m;
    psum[((size_t)b*1024 + o)*4 + ntile] = s;
  }
}

__global__ void head_reduce_kernel(const float* __restrict__ pmax, const float* __restrict__ psum,
                                   float* __restrict__ h2){
  int i = blockIdx.x*blockDim.x + threadIdx.x;
  if (i >= 16*1024) return;
  int b = i >> 10, o = i & 1023;
  const float* pm = pmax + (size_t)i*4;
  const float* ps = psum + (size_t)i*4;
  float mx = fmaxf(fmaxf(pm[0],pm[1]), fmaxf(pm[2],pm[3]));
  float sm = (ps[0]+ps[1])+(ps[2]+ps[3]);
  h2[(size_t)b*2048 + o] = mx;
  h2[(size_t)b*2048 + 1024 + o] = sm * (1.0f/256.0f);
}

// ---------------- head linears ----------------
__global__ __launch_bounds__(256) void lin1_kernel(const float* __restrict__ h2, const float* __restrict__ w,
    const float* __restrict__ g, const float* __restrict__ bb, float* __restrict__ y1){
  __shared__ float sh[2048];
  int b = blockIdx.y; int o = blockIdx.x*256 + threadIdx.x;
  for (int e=threadIdx.x; e<2048; e+=256) sh[e] = h2[(size_t)b*2048+e];
  __syncthreads();
  const float* wr = w + (size_t)o*2048;
  float acc=0.f;
  for (int c=0;c<2048;++c) acc = fmaf(wr[c], sh[c], acc);
  y1[(size_t)b*512+o] = lrelu(fmaf(acc, BN_INV*g[o], bb[o]));
}

__global__ __launch_bounds__(256) void lin2_kernel(const float* __restrict__ y1, const float* __restrict__ w,
    const float* __restrict__ lb, const float* __restrict__ g, const float* __restrict__ bb,
    float* __restrict__ y2){
  __shared__ float sh[512];
  int b = blockIdx.x; int o = threadIdx.x;
  for (int e=o; e<512; e+=256) sh[e]=y1[(size_t)b*512+e];
  __syncthreads();
  const float* wr = w + (size_t)o*512;
  float acc=0.f;
  for (int c=0;c<512;++c) acc = fmaf(wr[c], sh[c], acc);
  acc += lb[o];
  y2[(size_t)b*256+o] = lrelu(fmaf(acc, BN_INV*g[o], bb[o]));
}

__global__ __launch_bounds__(64) void lin3_kernel(const float* __restrict__ y2, const float* __restrict__ w,
    const float* __restrict__ lb, float* __restrict__ outp){
  __shared__ float sh[256];
  int b = blockIdx.x; int t = threadIdx.x;
  for (int e=t; e<256; e+=64) sh[e]=y2[(size_t)b*256+e];
  __syncthreads();
  if (t < 40){
    const float* wr = w + (size_t)t*256;
    float acc=0.f;
    for (int c=0;c<256;++c) acc = fmaf(wr[c], sh[c], acc);
    outp[(size_t)b*40+t] = acc + lb[t];
  }
}

extern "C" void kernel_launch(void* const* d_in, const int* in_sizes, int n_in,
                              void* d_out, int out_size, void* d_ws, size_t ws_size,
                              hipStream_t stream) {
  const float* x      = (const float*)d_in[0];
  const float* conv1w = (const float*)d_in[1];
  const float* bn1g   = (const float*)d_in[2];
  const float* bn1b   = (const float*)d_in[3];
  const float* conv2w = (const float*)d_in[4];
  const float* bn2g   = (const float*)d_in[5];
  const float* bn2b   = (const float*)d_in[6];
  const float* conv3w = (const float*)d_in[7];
  const float* bn3g   = (const float*)d_in[8];
  const float* bn3b   = (const float*)d_in[9];
  const float* conv5w = (const float*)d_in[10];
  const float* bn5g   = (const float*)d_in[11];
  const float* bn5b   = (const float*)d_in[12];
  const float* lin1w  = (const float*)d_in[13];
  const float* bn6g   = (const float*)d_in[14];
  const float* bn6b   = (const float*)d_in[15];
  const float* lin2w  = (const float*)d_in[16];
  const float* lin2b  = (const float*)d_in[17];
  const float* bn7g   = (const float*)d_in[18];
  const float* bn7b   = (const float*)d_in[19];
  const float* lin3w  = (const float*)d_in[20];
  const float* lin3b  = (const float*)d_in[21];
  float* outp = (float*)d_out;

  char* ws = (char*)d_ws;
  size_t off = 0;
  auto alloc = [&](size_t bytes)->char*{
    off = (off + 255) & ~(size_t)255;
    char* p = ws + off; off += bytes; return p;
  };
  const int B=16, N1=1024, N2=512, N3=256;
  float* pts1 = (float*)alloc((size_t)B*N1*3*4);
  int*   ieu1 = (int*)alloc((size_t)B*N1*KNB*4);
  float* eig1 = (float*)alloc((size_t)B*N1*3*4);
  int*   iei1 = (int*)alloc((size_t)B*N1*KNB*4);
  float* x1   = (float*)alloc((size_t)B*N1*64*4);
  int*   id2  = (int*)alloc((size_t)B*N2*4);
  float* pts2 = (float*)alloc((size_t)B*N2*3*4);
  float* x1d  = (float*)alloc((size_t)B*N2*64*4);
  int*   ieu2 = (int*)alloc((size_t)B*N2*KNB*4);
  float* eig2 = (float*)alloc((size_t)B*N2*3*4);
  int*   iei2 = (int*)alloc((size_t)B*N2*KNB*4);
  float* x2   = (float*)alloc((size_t)B*N2*64*4);
  int*   id3  = (int*)alloc((size_t)B*N3*4);
  float* pts3 = (float*)alloc((size_t)B*N3*3*4);
  float* x2d  = (float*)alloc((size_t)B*N3*64*4);
  float* x1dd = (float*)alloc((size_t)B*N3*64*4);
  int*   ieu3 = (int*)alloc((size_t)B*N3*KNB*4);
  float* eig3 = (float*)alloc((size_t)B*N3*3*4);
  int*   iei3 = (int*)alloc((size_t)B*N3*KNB*4);
  float* x3   = (float*)alloc((size_t)B*N3*128*4);
  float* pmax = (float*)alloc((size_t)B*1024*4*4);
  float* psum = (float*)alloc((size_t)B*1024*4*4);
  float* h2   = (float*)alloc((size_t)B*2048*4);
  float* y1   = (float*)alloc((size_t)B*512*4);
  float* y2   = (float*)alloc((size_t)B*256*4);
  float* W1q2 = (float*)alloc((size_t)64*64*4);
  float* W2q2 = (float*)alloc((size_t)64*64*4);
  float* Wbq2 = (float*)alloc((size_t)64*64*4);
  float* W1q3 = (float*)alloc((size_t)128*64*4);
  float* W2q3 = (float*)alloc((size_t)128*64*4);
  float* Wbq3 = (float*)alloc((size_t)128*64*4);

  combine_w_kernel<64><<<(64*64+255)/256, 256, 0, stream>>>(conv2w, W1q2, W2q2, Wbq2);
  combine_w_kernel<128><<<(128*64+255)/256, 256, 0, stream>>>(conv3w, W1q3, W2q3, Wbq3);
  transpose_x_kernel<<<(B*N1+255)/256, 256, 0, stream>>>(x, pts1, N1);
  knn_kernel<1024><<<dim3(256,16), 256, 0, stream>>>(pts1, ieu1);
  cov_eig_kernel<1024><<<(B*N1+255)/256, 256, 0, stream>>>(pts1, ieu1, eig1);
  knn_kernel<1024><<<dim3(256,16), 256, 0, stream>>>(eig1, iei1);
  stage1_kernel<<<B*N1, 64, 0, stream>>>(pts1, eig1, ieu1, iei1, conv1w, bn1g, bn1b, x1, N1);
  fps_kernel<1024,512><<<16, 64, 0, stream>>>(pts1, id2);
  gather_pts_kernel<<<(B*N2+255)/256, 256, 0, stream>>>(pts1, id2, pts2, N1, N2);
  gather_feat_kernel<<<(B*N2*64+255)/256, 256, 0, stream>>>(x1, id2, x1d, N1, N2, 64);
  knn_kernel<512><<<dim3(128,16), 256, 0, stream>>>(pts2, ieu2);
  cov_eig_kernel<512><<<(B*N2+255)/256, 256, 0, stream>>>(pts2, ieu2, eig2);
  knn_kernel<512><<<dim3(128,16), 256, 0, stream>>>(eig2, iei2);
  groupconv_kernel<64,512><<<B*N2, 64, 0, stream>>>(x1d, ieu2, iei2, W1q2, W2q2, Wbq2, bn2g, bn2b, x2);
  fps_kernel<512,256><<<16, 64, 0, stream>>>(pts2, id3);
  gather_pts_kernel<<<(B*N3+255)/256, 256, 0, stream>>>(pts2, id3, pts3, N2, N3);
  gather_feat_kernel<<<(B*N3*64+255)/256, 256, 0, stream>>>(x2, id3, x2d, N2, N3, 64);
  gather_feat_kernel<<<(B*N3*64+255)/256, 256, 0, stream>>>(x1d, id3, x1dd, N2, N3, 64);
  knn_kernel<256><<<dim3(64,16), 256, 0, stream>>>(pts3, ieu3);
  cov_eig_kernel<256><<<(B*N3+255)/256, 256, 0, stream>>>(pts3, ieu3, eig3);
  knn_kernel<256><<<dim3(64,16), 256, 0, stream>>>(eig3, iei3);
  groupconv_kernel<128,256><<<B*N3, 128, 0, stream>>>(x2d, ieu3, iei3, W1q3, W2q3, Wbq3, bn3g, bn3b, x3);
  conv5_gemm_kernel<<<dim3(16,4,16), 256, 0, stream>>>(x1dd, x2d, x3, conv5w, bn5g, bn5b, pmax, psum);
  head_reduce_kernel<<<(B*1024+255)/256, 256, 0, stream>>>(pmax, psum, h2);
  lin1_kernel<<<dim3(2,16), 256, 0, stream>>>(h2, lin1w, bn6g, bn6b, y1);
  lin2_kernel<<<16, 256, 0, stream>>>(y1, lin2w, lin2b, bn7g, bn7b, y2);
  lin3_kernel<<<16, 64, 0, stream>>>(y2, lin3w, lin3b, outp);
}